// Round 5
// baseline (552.653 us; speedup 1.0000x reference)
//
#include <hip/hip_runtime.h>
#include <cmath>

typedef __bf16 bf16;
typedef float f32x4 __attribute__((ext_vector_type(4)));
typedef __bf16 bf16x4 __attribute__((ext_vector_type(4)));
typedef __bf16 bf16x8 __attribute__((ext_vector_type(8)));

#define DEVI __device__ __forceinline__

// ---- problem dims ----
constexpr int Bn = 4, Tn = 2048, Cn = 1024, Hn = 16, HSn = 64;
constexpr int C3n = 3 * Cn;      // 3072
constexpr int BTn = Bn * Tn;     // 8192

// ---- workspace layout (bytes) ----
constexpr size_t OFF_WT_QKV = 0;           // 3072x1024 bf16
constexpr size_t OFF_WT_O   = 6291456;     // 1024x1024 bf16
constexpr size_t OFF_WT_FC  = 8388608;     // 4096x1024 bf16
constexpr size_t OFF_WT_PR  = 16777216;    // 1024x4096 bf16
constexpr size_t OFF_H      = 25165824;    // 8192x1024 bf16 (h / h2)
constexpr size_t OFF_Y      = 41943040;    // 8192x1024 bf16 (attn out)
constexpr size_t OFF_X1     = 58720256;    // 8192x1024 f32  (resid1)
constexpr size_t OFF_AMAX   = 92274688;    // 2 x u32
constexpr size_t OFF_QKV    = 92274944;    // 8192x3072 bf16
constexpr size_t OFF_G      = OFF_QKV;     // 8192x4096 bf16 (aliases qkv, dead by then)

// ---- d_out layout (float elements) ----
constexpr size_t OUT_X  = 0;          // (B,T,C)
constexpr size_t OUT_KQ = 8388608;    // (B,H,T,HS)
constexpr size_t OUT_KS = 16777216;   // scalar
constexpr size_t OUT_VQ = 16777217;   // (B,H,T,HS)
constexpr size_t OUT_VS = 25165825;   // scalar

// ============================================================
DEVI void g2l16(const void* g, void* l) {
  __builtin_amdgcn_global_load_lds(
      (__attribute__((address_space(1))) void*)g,
      (__attribute__((address_space(3))) void*)l, 16, 0, 0);
}

// exact-grade GELU: Abramowitz-Stegun 7.1.26 erf (|eps|<=1.5e-7), ~15 VALU + 1 exp
DEVI float gelu_f(float x) {
  const float ax = fabsf(x) * 0.7071067811865476f;
  const float t = 1.0f / (1.0f + 0.3275911f * ax);
  const float p = t * (0.254829592f + t * (-0.284496736f +
                  t * (1.421413741f + t * (-1.453152027f + t * 1.061405429f))));
  float er = 1.0f - p * __expf(-ax * ax);
  er = (x < 0.0f) ? -er : er;
  return 0.5f * x * (1.0f + er);
}

// ============================================================
// transpose + cast: W (K x N) f32 -> Wt (N x K) bf16
__global__ __launch_bounds__(256) void k_transpose(const float* __restrict__ W,
                                                   bf16* __restrict__ Wt,
                                                   int K, int N) {
  __shared__ float tile[32][33];
  const int n0 = blockIdx.x * 32, k0 = blockIdx.y * 32;
  const int tx = threadIdx.x, ty = threadIdx.y;   // block (32,8)
#pragma unroll
  for (int i = 0; i < 4; ++i) {
    int k = k0 + ty + i * 8;
    tile[ty + i * 8][tx] = W[(size_t)k * N + (n0 + tx)];
  }
  __syncthreads();
#pragma unroll
  for (int i = 0; i < 4; ++i) {
    int n = n0 + ty + i * 8;
    Wt[(size_t)n * K + (k0 + tx)] = (bf16)tile[tx][ty + i * 8];
  }
}

// ============================================================
// LayerNorm row of 1024, f32 in -> bf16 out.
__global__ __launch_bounds__(256) void k_ln(const float* __restrict__ x,
                                            const float* __restrict__ g,
                                            const float* __restrict__ b,
                                            bf16* __restrict__ out) {
  __shared__ float red[8];
  const int row = blockIdx.x, tid = threadIdx.x;
  const int lane = tid & 63, wv = tid >> 6;
  f32x4 v = ((const f32x4*)(x + (size_t)row * Cn))[tid];

  float s = v[0] + v[1] + v[2] + v[3];
  s += __shfl_down(s, 32); s += __shfl_down(s, 16); s += __shfl_down(s, 8);
  s += __shfl_down(s, 4);  s += __shfl_down(s, 2);  s += __shfl_down(s, 1);
  if (!lane) red[wv] = s;
  __syncthreads();
  const float mean = (red[0] + red[1] + red[2] + red[3]) * (1.0f / 1024.0f);
  __syncthreads();

  f32x4 d = v - mean;
  float s2 = d[0]*d[0] + d[1]*d[1] + d[2]*d[2] + d[3]*d[3];
  s2 += __shfl_down(s2, 32); s2 += __shfl_down(s2, 16); s2 += __shfl_down(s2, 8);
  s2 += __shfl_down(s2, 4);  s2 += __shfl_down(s2, 2);  s2 += __shfl_down(s2, 1);
  if (!lane) red[wv] = s2;
  __syncthreads();
  const float var = (red[0] + red[1] + red[2] + red[3]) * (1.0f / 1024.0f);
  const float inv = rsqrtf(var + 1e-5f);

  f32x4 gw = ((const f32x4*)g)[tid];
  f32x4 bb = ((const f32x4*)b)[tid];
  bf16x4 o;
#pragma unroll
  for (int j = 0; j < 4; ++j) o[j] = (bf16)(d[j] * inv * gw[j] + bb[j]);
  *(bf16x4*)(out + (size_t)row * Cn + tid * 4) = o;
}

// ============================================================
// 256-wide-N MFMA GEMM, BM in {128,256}, BK=64, 8 waves (2M x 4N).
// Deep-prefetch structure: per K-tile,
//   P0: read full B + A-quadrants 0,1 -> regs; lgkm0; MFMA Q0
//   P1: read A-quadrants 2,3 -> regs;   lgkm0; MFMA Q1; BARRIER
//   P2: stage A(kt+2)+B(kt+2) (distance 2); MFMA Q2,Q3; vmcnt(C); BARRIER
// C = 8 (BM256) / 6 (BM128) = loads issued per tile; vmcnt(0) only at kLast-1.
// Buffers are four distinct __shared__ objects so reads never alias DMA dests.
// Block-id remap: bijective chunked XCD swizzle (T1) -> consecutive tiles
// (sharing the B panel) land on the same XCD's L2. Requires nwg % 8 == 0.
#define VMCNT(N) asm volatile("s_waitcnt vmcnt(" #N ")" ::: "memory")
#define LGKM0()  asm volatile("s_waitcnt lgkmcnt(0)" ::: "memory")
#define BARW()   asm volatile("s_barrier" ::: "memory")
#define SCHEDB() __builtin_amdgcn_sched_barrier(0)

DEVI void stage_half(const bf16* __restrict__ G, int ldk, int row0, int k0,
                     bf16* dst, int w, int lane) {
  const int srow = lane >> 3;
  const int sch = ((lane & 7) ^ srow) * 8;
  const bf16* src = G + (size_t)(row0 + srow) * ldk + k0 + sch;
#pragma unroll
  for (int i = 0; i < 2; ++i) {
    const int g = 2 * w + i;
    g2l16(src + (size_t)(8 * g) * ldk, dst + g * 512);
  }
}

DEVI void read_b(const bf16* BsB, int wn, int l15, int quad, bf16x8 (&bv)[4][2]) {
#pragma unroll
  for (int nt = 0; nt < 4; ++nt)
#pragma unroll
    for (int kk = 0; kk < 2; ++kk) {
      const int row = wn * 64 + nt * 16 + l15;
      const int c = ((kk * 4 + quad) ^ (l15 & 7)) * 8;
      bv[nt][kk] = *(const bf16x8*)(BsB + row * 64 + c);
    }
}

template <int MR, int Q>
DEVI void read_aq(const bf16* AsB, int wm, int l15, int quad, bf16x8 (&af)[MR][2]) {
#pragma unroll
  for (int r = 0; r < MR; ++r)
#pragma unroll
    for (int kk = 0; kk < 2; ++kk) {
      const int row = wm * (MR * 64) + (Q * MR + r) * 16 + l15;
      const int c = ((kk * 4 + quad) ^ (l15 & 7)) * 8;
      af[r][kk] = *(const bf16x8*)(AsB + row * 64 + c);
    }
}

template <int MR, int MF, int Q>
DEVI void mfma_q(const bf16x8 (&af)[MR][2], const bf16x8 (&bv)[4][2],
                 f32x4 (&acc)[MF][4]) {
  __builtin_amdgcn_s_setprio(1);
#pragma unroll
  for (int r = 0; r < MR; ++r)
#pragma unroll
    for (int nt = 0; nt < 4; ++nt)
#pragma unroll
      for (int kk = 0; kk < 2; ++kk)
        acc[Q * MR + r][nt] = __builtin_amdgcn_mfma_f32_16x16x32_bf16(
            af[r][kk], bv[nt][kk], acc[Q * MR + r][nt], 0, 0, 0);
  __builtin_amdgcn_s_setprio(0);
}

template <int BM, int BUF>
DEVI void tile_iter(int kt, int kIters, const bf16* __restrict__ A,
                    const bf16* __restrict__ Bt, int K, int m0, int n0,
                    bf16* As0, bf16* As1, bf16* Bs0, bf16* Bs1,
                    f32x4 (&acc)[BM / 32][4], int w, int lane) {
  constexpr int MR = BM / 128, MF = BM / 32;
  const int l15 = lane & 15, quad = lane >> 4;
  const int wm = w >> 2, wn = w & 3;
  const bf16* AsB = BUF ? As1 : As0;   // read buffer (parity kt)
  const bf16* BsB = BUF ? Bs1 : Bs0;
  bf16* AsW = BUF ? As1 : As0;         // A(kt+2) dest: same parity
  bf16* BsW = BUF ? Bs1 : Bs0;

  bf16x8 bv[4][2];
  bf16x8 af0[MR][2], af1[MR][2], af2[MR][2], af3[MR][2];

  // ---- P0: full B + A quadrants 0,1 ----
  read_b(BsB, wn, l15, quad, bv);
  read_aq<MR, 0>(AsB, wm, l15, quad, af0);
  read_aq<MR, 1>(AsB, wm, l15, quad, af1);
  LGKM0(); SCHEDB();
  mfma_q<MR, MF, 0>(af0, bv, acc);
  SCHEDB();

  // ---- P1: A quadrants 2,3 ----
  read_aq<MR, 2>(AsB, wm, l15, quad, af2);
  read_aq<MR, 3>(AsB, wm, l15, quad, af3);
  LGKM0(); SCHEDB();
  mfma_q<MR, MF, 1>(af1, bv, acc);
  SCHEDB();
  BARW();   // all reads of this tile's buffers complete before overwrite

  // ---- P2: stage tile kt+2 (distance 2), compute Q2+Q3, counted drain ----
  if (kt + 2 < kIters) {
    stage_half(A, K, m0 + 0, (kt + 2) * 64, AsW + 0, w, lane);
    if constexpr (BM == 256)
      stage_half(A, K, m0 + 128, (kt + 2) * 64, AsW + 8192, w, lane);
    stage_half(Bt, K, n0 + 0,   (kt + 2) * 64, BsW + 0,    w, lane);
    stage_half(Bt, K, n0 + 128, (kt + 2) * 64, BsW + 8192, w, lane);
  }
  mfma_q<MR, MF, 2>(af2, bv, acc);
  mfma_q<MR, MF, 3>(af3, bv, acc);
  SCHEDB();
  if (kt + 2 < kIters) {
    if constexpr (BM == 256) { VMCNT(8); } else { VMCNT(6); }
    BARW();
  } else if (kt + 1 < kIters) {
    VMCNT(0);
    BARW();
  }
}

template <int BM, bool RES, bool GELU, bool AMAX, bool F32OUT>
__global__ __launch_bounds__(512, 2) void k_gemm256(const bf16* __restrict__ A,
                                                    const bf16* __restrict__ Bt,
                                                    const float* __restrict__ bias,
                                                    const float* __restrict__ res,
                                                    void* __restrict__ Cout,
                                                    unsigned int* __restrict__ amax,
                                                    int M, int N, int K) {
  constexpr int MR = BM / 128;   // m-frags per quadrant
  constexpr int MF = BM / 32;    // m-frags per wave
  __shared__ bf16 As0[BM * 64], As1[BM * 64];
  __shared__ bf16 Bs0[256 * 64], Bs1[256 * 64];
  __shared__ float redA[8];
  const int tid = threadIdx.x;
  const int lane = tid & 63, w = tid >> 6;
  const int wm = w >> 2, wn = w & 3;
  const int l15 = lane & 15, quad = lane >> 4;

  // ---- bijective chunked XCD swizzle (nwg % 8 == 0 for all our grids) ----
  const int gx = gridDim.x;
  const int nwg = gx * gridDim.y;
  const int cpx = nwg >> 3;
  int lin = (int)blockIdx.y * gx + (int)blockIdx.x;
  lin = (lin & 7) * cpx + (lin >> 3);
  const int m0 = (lin % gx) * BM, n0 = (lin / gx) * 256;

  const int kIters = K >> 6;
  (void)M;

  // ---- prologue: A(0),B(0) -> buf0; A(1),B(1) -> buf1 ----
  stage_half(A, K, m0 + 0, 0, As0 + 0, w, lane);
  if constexpr (BM == 256) stage_half(A, K, m0 + 128, 0, As0 + 8192, w, lane);
  stage_half(Bt, K, n0 + 0,   0, Bs0 + 0,    w, lane);
  stage_half(Bt, K, n0 + 128, 0, Bs0 + 8192, w, lane);
  stage_half(A, K, m0 + 0, 64, As1 + 0, w, lane);
  if constexpr (BM == 256) stage_half(A, K, m0 + 128, 64, As1 + 8192, w, lane);
  stage_half(Bt, K, n0 + 0,   64, Bs1 + 0,    w, lane);
  stage_half(Bt, K, n0 + 128, 64, Bs1 + 8192, w, lane);
  if constexpr (BM == 256) { VMCNT(8); } else { VMCNT(6); }
  BARW();

  f32x4 acc[MF][4] = {};

  const int nPairs = kIters >> 1;
  for (int p = 0; p < nPairs; ++p) {
    tile_iter<BM, 0>(2 * p,     kIters, A, Bt, K, m0, n0, As0, As1, Bs0, Bs1, acc, w, lane);
    tile_iter<BM, 1>(2 * p + 1, kIters, A, Bt, K, m0, n0, As0, As1, Bs0, Bs1, acc, w, lane);
  }

  // ---- epilogue ----
  const int colB = n0 + wn * 64 + l15;
  const int rowB = m0 + wm * (BM / 2) + (quad << 2);
  float lm = 0.0f;
#pragma unroll
  for (int mt = 0; mt < MF; ++mt) {
#pragma unroll
    for (int nt = 0; nt < 4; ++nt) {
      const int col = colB + nt * 16;
      const float bval = bias[col];
#pragma unroll
      for (int r = 0; r < 4; ++r) {
        const int row = rowB + mt * 16 + r;
        float val = acc[mt][nt][r] + bval;
        if (GELU) val = gelu_f(val);
        if (RES)  val += res[(size_t)row * N + col];
        if (AMAX) lm = fmaxf(lm, fabsf(val));
        if (F32OUT) ((float*)Cout)[(size_t)row * N + col] = val;
        else        ((bf16*)Cout)[(size_t)row * N + col] = (bf16)val;
      }
    }
  }

  if (AMAX) {
    const int cls = n0 >> 10;   // 0=Q, 1=K, 2=V (256-tile never crosses a class)
    if (cls > 0) {
      lm = fmaxf(lm, __shfl_xor(lm, 1));
      lm = fmaxf(lm, __shfl_xor(lm, 2));
      lm = fmaxf(lm, __shfl_xor(lm, 4));
      lm = fmaxf(lm, __shfl_xor(lm, 8));
      lm = fmaxf(lm, __shfl_xor(lm, 16));
      lm = fmaxf(lm, __shfl_xor(lm, 32));
      if (!lane) redA[w] = lm;
      __syncthreads();
      if (tid == 0) {
        float m8 = redA[0];
#pragma unroll
        for (int i = 1; i < 8; ++i) m8 = fmaxf(m8, redA[i]);
        atomicMax(amax + (cls - 1), __float_as_uint(m8));
      }
    }
  }
}

// ============================================================
__global__ __launch_bounds__(256) void k_init(unsigned int* amax) {
  if (threadIdx.x < 2) amax[threadIdx.x] = 0u;
}

__global__ __launch_bounds__(256) void k_quant(const bf16* __restrict__ qkv,
                                               const unsigned int* __restrict__ amax,
                                               float* __restrict__ out) {
  const float ka = __uint_as_float(amax[0]);
  const float va = __uint_as_float(amax[1]);
  const float ks = ka > 0.0f ? ka / 127.0f : 1.0f;
  const float vs = va > 0.0f ? va / 127.0f : 1.0f;
  if (blockIdx.x == 0 && threadIdx.x == 0) { out[OUT_KS] = ks; out[OUT_VS] = vs; }
  const float kinv = 1.0f / ks, vinv = 1.0f / vs;
  const size_t nchunks = 1048576;
  const size_t stride = (size_t)gridDim.x * blockDim.x;
  for (size_t ci = (size_t)blockIdx.x * blockDim.x + threadIdx.x; ci < nchunks; ci += stride) {
    const int d0 = (int)(ci & 7) * 8;
    const int t  = (int)(ci >> 3) & 2047;
    const int h  = (int)(ci >> 14) & 15;
    const int b  = (int)(ci >> 18);
    const size_t src = ((size_t)(b * Tn + t)) * C3n + h * HSn + d0;
    bf16x8 k8 = *(const bf16x8*)(qkv + src + Cn);
    bf16x8 v8 = *(const bf16x8*)(qkv + src + 2 * Cn);
    float kq[8], vq[8];
#pragma unroll
    for (int j = 0; j < 8; ++j) {
      kq[j] = fminf(fmaxf(rintf((float)k8[j] * kinv), -127.0f), 127.0f);
      vq[j] = fminf(fmaxf(rintf((float)v8[j] * vinv), -127.0f), 127.0f);
    }
    const size_t oi = ci * 8;
    f32x4 a0 = {kq[0], kq[1], kq[2], kq[3]};
    f32x4 a1 = {kq[4], kq[5], kq[6], kq[7]};
    *(f32x4*)(out + OUT_KQ + oi)     = a0;
    *(f32x4*)(out + OUT_KQ + oi + 4) = a1;
    float* vdst = out + OUT_VQ + oi;
#pragma unroll
    for (int j = 0; j < 8; ++j) vdst[j] = vq[j];
  }
}

// ============================================================
// Transposed-score MFMA flash attention, causal, q-tile=128 (2 q-groups/wave),
// double-buffered K/V. K/V fragments are wave-invariant -> amortized over 2
// q-groups. Block = (b,h,128 q rows), 4 waves. LDS 48 KB -> 3 blocks/CU.
__global__ __launch_bounds__(256, 3) void k_attn(const bf16* __restrict__ qkv,
                                                 bf16* __restrict__ y) {
  __shared__ bf16 Ks[2][64 * 64];
  __shared__ bf16 Vt[2][64 * 64];
  __shared__ bf16 Pt[4][2][16 * 64];   // per wave, per q-group

  const int tid = threadIdx.x;
  const int lane = tid & 63;
  const int w = tid >> 6;
  const int quad = lane >> 4;
  const int l15 = lane & 15;

  const int bh = blockIdx.x;               // fastest dim: big tiles dispatch first
  const int qt = 15 - (int)blockIdx.y;
  const int b = bh >> 4, h = bh & 15;
  const int q0 = qt * 128;
  const int ktMax = 2 * qt + 1;

  const bf16* qkv_b = qkv + (size_t)b * Tn * C3n + h * HSn;
  const bf16* kbase = qkv_b + Cn;
  const bf16* vbase = qkv_b + 2 * Cn;

  const int srow = lane >> 3;
  const int schunk = ((lane & 7) ^ srow) * 8;

  // ---- Q fragments for both groups (from global, once) ----
  const bf16* q0p = qkv_b + (size_t)(q0 + 16 * w + l15) * C3n;
  const bf16* q1p = q0p + (size_t)64 * C3n;
  bf16x8 qf[2][2];
  qf[0][0] = *(const bf16x8*)(q0p + quad * 8);
  qf[0][1] = *(const bf16x8*)(q0p + 32 + quad * 8);
  qf[1][0] = *(const bf16x8*)(q1p + quad * 8);
  qf[1][1] = *(const bf16x8*)(q1p + 32 + quad * 8);

  // ---- prologue: K(0), V(0) ----
  g2l16(kbase + (size_t)(8 * w + srow) * C3n + schunk, (bf16*)Ks[0] + w * 512);
  g2l16(kbase + (size_t)(8 * (w + 4) + srow) * C3n + schunk, (bf16*)Ks[0] + (w + 4) * 512);
  bf16x8 v0 = *(const bf16x8*)(vbase + (size_t)lane * C3n + w * 8);
  bf16x8 v1 = *(const bf16x8*)(vbase + (size_t)lane * C3n + (w + 4) * 8);
  __builtin_amdgcn_s_waitcnt(0);
#pragma unroll
  for (int j = 0; j < 8; ++j) {   // Vt[d][kc] swizzled; d&7 == j
    Vt[0][(w * 8 + j) * 64 + ((srow ^ j) << 3) + (lane & 7)] = v0[j];
    Vt[0][((w + 4) * 8 + j) * 64 + ((srow ^ j) << 3) + (lane & 7)] = v1[j];
  }
  __syncthreads();

  f32x4 Od[2][4] = {};
  float m_i[2] = {-INFINITY, -INFINITY};
  float l_i[2] = {0.0f, 0.0f};

  for (int kt = 0; kt <= ktMax; ++kt) {
    const int bsel = kt & 1;

    // ---- issue next tile's loads ----
    bf16x8 nv0, nv1;
    if (kt < ktMax) {
      const int kv1 = (kt + 1) * 64;
      g2l16(kbase + (size_t)(kv1 + 8 * w + srow) * C3n + schunk,
            (bf16*)Ks[bsel ^ 1] + w * 512);
      g2l16(kbase + (size_t)(kv1 + 8 * (w + 4) + srow) * C3n + schunk,
            (bf16*)Ks[bsel ^ 1] + (w + 4) * 512);
      nv0 = *(const bf16x8*)(vbase + (size_t)(kv1 + lane) * C3n + w * 8);
      nv1 = *(const bf16x8*)(vbase + (size_t)(kv1 + lane) * C3n + (w + 4) * 8);
    }

    // ---- S^T = K Q^T for both q-groups (K frags shared) ----
    const bf16* KsB = Ks[bsel];
    f32x4 S0[4] = {}, S1[4] = {};
#pragma unroll
    for (int ks = 0; ks < 2; ++ks)
#pragma unroll
      for (int nt = 0; nt < 4; ++nt) {
        const int rn = nt * 16 + l15;
        const int c = ((ks * 4 + quad) ^ (l15 & 7)) * 8;
        bf16x8 kf = *(const bf16x8*)(KsB + rn * 64 + c);
        S0[nt] = __builtin_amdgcn_mfma_f32_16x16x32_bf16(kf, qf[0][ks], S0[nt], 0, 0, 0);
        S1[nt] = __builtin_amdgcn_mfma_f32_16x16x32_bf16(kf, qf[1][ks], S1[nt], 0, 0, 0);
      }

    // ---- online softmax per group (lane owns q = g*64 + 16w + l15) ----
    const int qloc = 16 * w + l15;
    const int th[2] = { kt < 2 * qt ? 64 : (kt == 2 * qt ? qloc : -1),
                        kt < ktMax ? 64 : qloc };
    f32x4* Sg[2] = {S0, S1};
#pragma unroll
    for (int g = 0; g < 2; ++g) {
      float s[4][4];
      float mx = -INFINITY;
#pragma unroll
      for (int nt = 0; nt < 4; ++nt)
#pragma unroll
        for (int r = 0; r < 4; ++r) {
          float v = Sg[g][nt][r] * 0.125f;
          if (nt * 16 + quad * 4 + r > th[g]) v = -INFINITY;
          s[nt][r] = v;
          mx = fmaxf(mx, v);
        }
      mx = fmaxf(mx, __shfl_xor(mx, 16));
      mx = fmaxf(mx, __shfl_xor(mx, 32));
      const float mn = fmaxf(m_i[g], mx);
      const float al = __expf(m_i[g] - mn);
      m_i[g] = mn;
      float rsum = 0.0f;
      bf16x4 pk[4];
#pragma unroll
      for (int nt = 0; nt < 4; ++nt)
#pragma unroll
        for (int r = 0; r < 4; ++r) {
          const float p = __expf(s[nt][r] - mn);
          rsum += p;
          pk[nt][r] = (bf16)p;
        }
      rsum += __shfl_xor(rsum, 16);
      rsum += __shfl_xor(rsum, 32);
      l_i[g] = l_i[g] * al + rsum;
#pragma unroll
      for (int dt = 0; dt < 4; ++dt) Od[g][dt] *= al;
#pragma unroll
      for (int nt = 0; nt < 4; ++nt) {
        const int phys = (nt * 2 + (quad >> 1)) ^ (l15 & 7);
        *(bf16x4*)(&Pt[w][g][0] + l15 * 64 + phys * 8 + (quad & 1) * 4) = pk[nt];
      }
    }

    // ---- O^T += V^T P^T (V frags shared across groups) ----
    const bf16* VtB = Vt[bsel];
#pragma unroll
    for (int ks2 = 0; ks2 < 2; ++ks2) {
      const int pc = ((ks2 * 4 + quad) ^ (l15 & 7)) * 8;
      bf16x8 pf0 = *(const bf16x8*)(&Pt[w][0][0] + l15 * 64 + pc);
      bf16x8 pf1 = *(const bf16x8*)(&Pt[w][1][0] + l15 * 64 + pc);
#pragma unroll
      for (int dt = 0; dt < 4; ++dt) {
        const int d = dt * 16 + l15;
        bf16x8 vf = *(const bf16x8*)(VtB + d * 64 + pc);   // d&7 == l15&7
        Od[0][dt] = __builtin_amdgcn_mfma_f32_16x16x32_bf16(vf, pf0, Od[0][dt], 0, 0, 0);
        Od[1][dt] = __builtin_amdgcn_mfma_f32_16x16x32_bf16(vf, pf1, Od[1][dt], 0, 0, 0);
      }
    }

    // ---- drain next-tile loads, publish Vt[b^1], one barrier ----
    if (kt < ktMax) {
      __builtin_amdgcn_s_waitcnt(0);
#pragma unroll
      for (int j = 0; j < 8; ++j) {
        Vt[bsel ^ 1][(w * 8 + j) * 64 + ((srow ^ j) << 3) + (lane & 7)] = nv0[j];
        Vt[bsel ^ 1][((w + 4) * 8 + j) * 64 + ((srow ^ j) << 3) + (lane & 7)] = nv1[j];
      }
      __syncthreads();
    }
  }

  // ---- write y (B,T,C) ----
#pragma unroll
  for (int g = 0; g < 2; ++g) {
    const float invl = 1.0f / l_i[g];
    const size_t yb = ((size_t)b * Tn + q0 + g * 64 + 16 * w + l15) * Cn + h * HSn;
#pragma unroll
    for (int dt = 0; dt < 4; ++dt) {
      bf16x4 o;
#pragma unroll
      for (int r = 0; r < 4; ++r) o[r] = (bf16)(Od[g][dt][r] * invl);
      *(bf16x4*)(y + yb + dt * 16 + quad * 4) = o;
    }
  }
}

// ============================================================
extern "C" void kernel_launch(void* const* d_in, const int* in_sizes, int n_in,
                              void* d_out, int out_size, void* d_ws, size_t ws_size,
                              hipStream_t stream) {
  const float* x     = (const float*)d_in[0];
  const float* ln1w  = (const float*)d_in[1];
  const float* ln1b  = (const float*)d_in[2];
  const float* Wqkv  = (const float*)d_in[3];
  const float* bqkv  = (const float*)d_in[4];
  const float* Wo    = (const float*)d_in[5];
  const float* bo    = (const float*)d_in[6];
  const float* ln2w  = (const float*)d_in[7];
  const float* ln2b  = (const float*)d_in[8];
  const float* Wfc   = (const float*)d_in[9];
  const float* bfc   = (const float*)d_in[10];
  const float* Wpr   = (const float*)d_in[11];
  const float* bpr   = (const float*)d_in[12];

  char* ws = (char*)d_ws;
  bf16*  Wt_qkv = (bf16*)(ws + OFF_WT_QKV);
  bf16*  Wt_o   = (bf16*)(ws + OFF_WT_O);
  bf16*  Wt_fc  = (bf16*)(ws + OFF_WT_FC);
  bf16*  Wt_pr  = (bf16*)(ws + OFF_WT_PR);
  bf16*  h      = (bf16*)(ws + OFF_H);
  bf16*  ybf    = (bf16*)(ws + OFF_Y);
  float* x1     = (float*)(ws + OFF_X1);
  unsigned int* amax = (unsigned int*)(ws + OFF_AMAX);
  bf16*  qkvbf  = (bf16*)(ws + OFF_QKV);
  bf16*  g      = (bf16*)(ws + OFF_G);
  float* out    = (float*)d_out;

  const dim3 tb(32, 8);
  k_transpose<<<dim3(96, 32),  tb, 0, stream>>>(Wqkv, Wt_qkv, 1024, 3072);
  k_transpose<<<dim3(32, 32),  tb, 0, stream>>>(Wo,   Wt_o,   1024, 1024);
  k_transpose<<<dim3(128, 32), tb, 0, stream>>>(Wfc,  Wt_fc,  1024, 4096);
  k_transpose<<<dim3(32, 128), tb, 0, stream>>>(Wpr,  Wt_pr,  4096, 1024);
  k_init<<<1, 64, 0, stream>>>(amax);

  k_ln<<<BTn, 256, 0, stream>>>(x, ln1w, ln1b, h);
  // qkv = h @ Wqkv + b, fused per-tensor absmax of K,V
  // BM=128 -> grid 64x12 = 768 blocks = 3 exact dispatch rounds (no idle tail)
  k_gemm256<128, false, false, true, false><<<dim3(64, 12), 512, 0, stream>>>(
      h, Wt_qkv, bqkv, nullptr, qkvbf, amax, 8192, 3072, 1024);
  k_quant<<<2048, 256, 0, stream>>>(qkvbf, amax, out);
  k_attn<<<dim3(64, 16), 256, 0, stream>>>(qkvbf, ybf);
  // x1 = y @ Wo + bo + x   (grid 64x4 = 256 blocks, one full round)
  k_gemm256<128, true, false, false, true><<<dim3(64, 4), 512, 0, stream>>>(
      ybf, Wt_o, bo, x, x1, nullptr, 8192, 1024, 1024);
  k_ln<<<BTn, 256, 0, stream>>>(x1, ln2w, ln2b, h);
  // g = gelu(h @ Wfc + b)
  k_gemm256<256, false, true, false, false><<<dim3(32, 16), 512, 0, stream>>>(
      h, Wt_fc, bfc, nullptr, g, nullptr, 8192, 4096, 1024);
  // out = g @ Wpr + bpr + x1
  k_gemm256<128, true, false, false, true><<<dim3(64, 4), 512, 0, stream>>>(
      g, Wt_pr, bpr, x1, out, nullptr, 8192, 1024, 4096);
}

// Round 7
// 527.086 us; speedup vs baseline: 1.0485x; 1.0485x over previous
//
#include <hip/hip_runtime.h>
#include <cmath>

typedef __bf16 bf16;
typedef float f32x4 __attribute__((ext_vector_type(4)));
typedef __bf16 bf16x4 __attribute__((ext_vector_type(4)));
typedef __bf16 bf16x8 __attribute__((ext_vector_type(8)));

#define DEVI __device__ __forceinline__

// ---- problem dims ----
constexpr int Bn = 4, Tn = 2048, Cn = 1024, Hn = 16, HSn = 64;
constexpr int C3n = 3 * Cn;      // 3072
constexpr int BTn = Bn * Tn;     // 8192

// ---- workspace layout (bytes) ----
constexpr size_t OFF_WT_QKV = 0;           // 3072x1024 bf16
constexpr size_t OFF_WT_O   = 6291456;     // 1024x1024 bf16
constexpr size_t OFF_WT_FC  = 8388608;     // 4096x1024 bf16
constexpr size_t OFF_WT_PR  = 16777216;    // 1024x4096 bf16
constexpr size_t OFF_H      = 25165824;    // 8192x1024 bf16 (h / h2)
constexpr size_t OFF_Y      = 41943040;    // 8192x1024 bf16 (attn out)
constexpr size_t OFF_X1     = 58720256;    // 8192x1024 f32  (resid1)
constexpr size_t OFF_AMAX   = 92274688;    // 2 x u32
constexpr size_t OFF_QKV    = 92274944;    // 8192x3072 bf16
constexpr size_t OFF_G      = OFF_QKV;     // 8192x4096 bf16 (aliases qkv, dead by then)

// ---- d_out layout (float elements) ----
constexpr size_t OUT_X  = 0;          // (B,T,C)
constexpr size_t OUT_KQ = 8388608;    // (B,H,T,HS)
constexpr size_t OUT_KS = 16777216;   // scalar
constexpr size_t OUT_VQ = 16777217;   // (B,H,T,HS)
constexpr size_t OUT_VS = 25165825;   // scalar

// ============================================================
DEVI void g2l16(const void* g, void* l) {
  __builtin_amdgcn_global_load_lds(
      (__attribute__((address_space(1))) void*)g,
      (__attribute__((address_space(3))) void*)l, 16, 0, 0);
}

// exact-grade GELU: Abramowitz-Stegun 7.1.26 erf (|eps|<=1.5e-7), ~15 VALU + 1 exp
DEVI float gelu_f(float x) {
  const float ax = fabsf(x) * 0.7071067811865476f;
  const float t = 1.0f / (1.0f + 0.3275911f * ax);
  const float p = t * (0.254829592f + t * (-0.284496736f +
                  t * (1.421413741f + t * (-1.453152027f + t * 1.061405429f))));
  float er = 1.0f - p * __expf(-ax * ax);
  er = (x < 0.0f) ? -er : er;
  return 0.5f * x * (1.0f + er);
}

// ============================================================
// transpose + cast: W (K x N) f32 -> Wt (N x K) bf16
__global__ __launch_bounds__(256) void k_transpose(const float* __restrict__ W,
                                                   bf16* __restrict__ Wt,
                                                   int K, int N) {
  __shared__ float tile[32][33];
  const int n0 = blockIdx.x * 32, k0 = blockIdx.y * 32;
  const int tx = threadIdx.x, ty = threadIdx.y;   // block (32,8)
#pragma unroll
  for (int i = 0; i < 4; ++i) {
    int k = k0 + ty + i * 8;
    tile[ty + i * 8][tx] = W[(size_t)k * N + (n0 + tx)];
  }
  __syncthreads();
#pragma unroll
  for (int i = 0; i < 4; ++i) {
    int n = n0 + ty + i * 8;
    Wt[(size_t)n * K + (k0 + tx)] = (bf16)tile[tx][ty + i * 8];
  }
}

// ============================================================
// LayerNorm row of 1024, f32 in -> bf16 out.
__global__ __launch_bounds__(256) void k_ln(const float* __restrict__ x,
                                            const float* __restrict__ g,
                                            const float* __restrict__ b,
                                            bf16* __restrict__ out) {
  __shared__ float red[8];
  const int row = blockIdx.x, tid = threadIdx.x;
  const int lane = tid & 63, wv = tid >> 6;
  f32x4 v = ((const f32x4*)(x + (size_t)row * Cn))[tid];

  float s = v[0] + v[1] + v[2] + v[3];
  s += __shfl_down(s, 32); s += __shfl_down(s, 16); s += __shfl_down(s, 8);
  s += __shfl_down(s, 4);  s += __shfl_down(s, 2);  s += __shfl_down(s, 1);
  if (!lane) red[wv] = s;
  __syncthreads();
  const float mean = (red[0] + red[1] + red[2] + red[3]) * (1.0f / 1024.0f);
  __syncthreads();

  f32x4 d = v - mean;
  float s2 = d[0]*d[0] + d[1]*d[1] + d[2]*d[2] + d[3]*d[3];
  s2 += __shfl_down(s2, 32); s2 += __shfl_down(s2, 16); s2 += __shfl_down(s2, 8);
  s2 += __shfl_down(s2, 4);  s2 += __shfl_down(s2, 2);  s2 += __shfl_down(s2, 1);
  if (!lane) red[wv] = s2;
  __syncthreads();
  const float var = (red[0] + red[1] + red[2] + red[3]) * (1.0f / 1024.0f);
  const float inv = rsqrtf(var + 1e-5f);

  f32x4 gw = ((const f32x4*)g)[tid];
  f32x4 bb = ((const f32x4*)b)[tid];
  bf16x4 o;
#pragma unroll
  for (int j = 0; j < 4; ++j) o[j] = (bf16)(d[j] * inv * gw[j] + bb[j]);
  *(bf16x4*)(out + (size_t)row * Cn + tid * 4) = o;
}

// ============================================================
// 128x128-tile MFMA GEMM, BK=64, 512 threads (8 waves, 2M x 4N; wave tile 64x32).
// LDS = 4 x 16KB distinct buffers -> 64KB/block -> 2 blocks/CU (16 waves/CU):
// when one block sits in its barrier/drain, the co-resident block issues MFMA
// (m114 overlap). R4's 3-phase distance-2 pipeline per K-tile:
//   P0: read full B + A-frag 0,1 -> regs; lgkm0; MFMA Q0
//   P1: read A-frag 2,3 -> regs;  lgkm0; MFMA Q1; BARRIER
//   P2: stage A(kt+2)+B(kt+2);    MFMA Q2,Q3; vmcnt(4); BARRIER
// 4 loads/thread/K-tile; steady-state vmcnt(4) leaves tile kt+2 in flight;
// vmcnt(0) only at kt == kIters-2.
#define VMCNT(N) asm volatile("s_waitcnt vmcnt(" #N ")" ::: "memory")
#define LGKM0()  asm volatile("s_waitcnt lgkmcnt(0)" ::: "memory")
#define BARW()   asm volatile("s_barrier" ::: "memory")
#define SCHEDB() __builtin_amdgcn_sched_barrier(0)

DEVI void stage_half(const bf16* __restrict__ G, int ldk, int row0, int k0,
                     bf16* dst, int w, int lane) {
  const int srow = lane >> 3;
  const int sch = ((lane & 7) ^ srow) * 8;
  const bf16* src = G + (size_t)(row0 + srow) * ldk + k0 + sch;
#pragma unroll
  for (int i = 0; i < 2; ++i) {
    const int g = 2 * w + i;
    g2l16(src + (size_t)(8 * g) * ldk, dst + g * 512);
  }
}

DEVI void read_b(const bf16* BsB, int wn, int l15, int quad, bf16x8 (&bv)[2][2]) {
#pragma unroll
  for (int nt = 0; nt < 2; ++nt)
#pragma unroll
    for (int kk = 0; kk < 2; ++kk) {
      const int row = wn * 32 + nt * 16 + l15;
      const int c = ((kk * 4 + quad) ^ (l15 & 7)) * 8;
      bv[nt][kk] = *(const bf16x8*)(BsB + row * 64 + c);
    }
}

template <int Q>
DEVI void read_aq(const bf16* AsB, int wm, int l15, int quad, bf16x8 (&af)[2]) {
#pragma unroll
  for (int kk = 0; kk < 2; ++kk) {
    const int row = wm * 64 + Q * 16 + l15;
    const int c = ((kk * 4 + quad) ^ (l15 & 7)) * 8;
    af[kk] = *(const bf16x8*)(AsB + row * 64 + c);
  }
}

template <int Q>
DEVI void mfma_q(const bf16x8 (&af)[2], const bf16x8 (&bv)[2][2],
                 f32x4 (&acc)[4][2]) {
  __builtin_amdgcn_s_setprio(1);
#pragma unroll
  for (int nt = 0; nt < 2; ++nt)
#pragma unroll
    for (int kk = 0; kk < 2; ++kk)
      acc[Q][nt] = __builtin_amdgcn_mfma_f32_16x16x32_bf16(
          af[kk], bv[nt][kk], acc[Q][nt], 0, 0, 0);
  __builtin_amdgcn_s_setprio(0);
}

template <int BUF>
DEVI void tile_iter(int kt, int kIters, const bf16* __restrict__ A,
                    const bf16* __restrict__ Bt, int K, int m0, int n0,
                    bf16* As0, bf16* As1, bf16* Bs0, bf16* Bs1,
                    f32x4 (&acc)[4][2], int w, int lane) {
  const int l15 = lane & 15, quad = lane >> 4;
  const int wm = w >> 2, wn = w & 3;
  const bf16* AsB = BUF ? As1 : As0;   // read buffer (parity kt)
  const bf16* BsB = BUF ? Bs1 : Bs0;
  bf16* AsW = BUF ? As1 : As0;         // dest for tile kt+2 (same parity)
  bf16* BsW = BUF ? Bs1 : Bs0;

  bf16x8 bv[2][2];
  bf16x8 af0[2], af1[2], af2[2], af3[2];

  // ---- P0: full B + A frags 0,1 ----
  read_b(BsB, wn, l15, quad, bv);
  read_aq<0>(AsB, wm, l15, quad, af0);
  read_aq<1>(AsB, wm, l15, quad, af1);
  LGKM0(); SCHEDB();
  mfma_q<0>(af0, bv, acc);
  SCHEDB();

  // ---- P1: A frags 2,3 ----
  read_aq<2>(AsB, wm, l15, quad, af2);
  read_aq<3>(AsB, wm, l15, quad, af3);
  LGKM0(); SCHEDB();
  mfma_q<1>(af1, bv, acc);
  SCHEDB();
  BARW();   // all reads of this tile's buffers complete before overwrite

  // ---- P2: stage tile kt+2 (distance 2), compute Q2+Q3, counted drain ----
  if (kt + 2 < kIters) {
    stage_half(A,  K, m0, (kt + 2) * 64, AsW, w, lane);
    stage_half(Bt, K, n0, (kt + 2) * 64, BsW, w, lane);
  }
  mfma_q<2>(af2, bv, acc);
  mfma_q<3>(af3, bv, acc);
  SCHEDB();
  if (kt + 2 < kIters) {
    VMCNT(4);
    BARW();
  } else if (kt + 1 < kIters) {
    VMCNT(0);
    BARW();
  }
}

template <bool RES, bool GELU, bool AMAX, bool F32OUT>
__global__ __launch_bounds__(512, 4) void k_gemmT(const bf16* __restrict__ A,
                                                  const bf16* __restrict__ Bt,
                                                  const float* __restrict__ bias,
                                                  const float* __restrict__ res,
                                                  void* __restrict__ Cout,
                                                  unsigned int* __restrict__ amax,
                                                  int M, int N, int K) {
  __shared__ bf16 As0[128 * 64], As1[128 * 64];
  __shared__ bf16 Bs0[128 * 64], Bs1[128 * 64];
  __shared__ float redA[8];
  const int tid = threadIdx.x;
  const int lane = tid & 63, w = tid >> 6;
  const int wm = w >> 2, wn = w & 3;
  const int l15 = lane & 15, quad = lane >> 4;
  const int m0 = blockIdx.x * 128, n0 = blockIdx.y * 128;
  const int kIters = K >> 6;
  (void)M;

  // ---- prologue: tile0 -> buf0, tile1 -> buf1 ----
  stage_half(A,  K, m0, 0,  As0, w, lane);
  stage_half(Bt, K, n0, 0,  Bs0, w, lane);
  stage_half(A,  K, m0, 64, As1, w, lane);
  stage_half(Bt, K, n0, 64, Bs1, w, lane);
  VMCNT(4);
  BARW();

  f32x4 acc[4][2] = {};

  const int nPairs = kIters >> 1;
  for (int p = 0; p < nPairs; ++p) {
    tile_iter<0>(2 * p,     kIters, A, Bt, K, m0, n0, As0, As1, Bs0, Bs1, acc, w, lane);
    tile_iter<1>(2 * p + 1, kIters, A, Bt, K, m0, n0, As0, As1, Bs0, Bs1, acc, w, lane);
  }

  // ---- epilogue ----
  const int colB = n0 + wn * 32 + l15;
  const int rowB = m0 + wm * 64 + (quad << 2);
  float lm = 0.0f;
#pragma unroll
  for (int mt = 0; mt < 4; ++mt) {
#pragma unroll
    for (int nt = 0; nt < 2; ++nt) {
      const int col = colB + nt * 16;
      const float bval = bias[col];
#pragma unroll
      for (int r = 0; r < 4; ++r) {
        const int row = rowB + mt * 16 + r;
        float val = acc[mt][nt][r] + bval;
        if (GELU) val = gelu_f(val);
        if (RES)  val += res[(size_t)row * N + col];
        if (AMAX) lm = fmaxf(lm, fabsf(val));
        if (F32OUT) ((float*)Cout)[(size_t)row * N + col] = val;
        else        ((bf16*)Cout)[(size_t)row * N + col] = (bf16)val;
      }
    }
  }

  if (AMAX) {
    const int cls = n0 >> 10;   // 0=Q, 1=K, 2=V (128-tile never crosses a class)
    if (cls > 0) {
      lm = fmaxf(lm, __shfl_xor(lm, 1));
      lm = fmaxf(lm, __shfl_xor(lm, 2));
      lm = fmaxf(lm, __shfl_xor(lm, 4));
      lm = fmaxf(lm, __shfl_xor(lm, 8));
      lm = fmaxf(lm, __shfl_xor(lm, 16));
      lm = fmaxf(lm, __shfl_xor(lm, 32));
      if (!lane) redA[w] = lm;
      __syncthreads();
      if (tid == 0) {
        float m8 = redA[0];
#pragma unroll
        for (int i = 1; i < 8; ++i) m8 = fmaxf(m8, redA[i]);
        atomicMax(amax + (cls - 1), __float_as_uint(m8));
      }
    }
  }
}

// ============================================================
__global__ __launch_bounds__(256) void k_init(unsigned int* amax) {
  if (threadIdx.x < 2) amax[threadIdx.x] = 0u;
}

__global__ __launch_bounds__(256) void k_quant(const bf16* __restrict__ qkv,
                                               const unsigned int* __restrict__ amax,
                                               float* __restrict__ out) {
  const float ka = __uint_as_float(amax[0]);
  const float va = __uint_as_float(amax[1]);
  const float ks = ka > 0.0f ? ka / 127.0f : 1.0f;
  const float vs = va > 0.0f ? va / 127.0f : 1.0f;
  if (blockIdx.x == 0 && threadIdx.x == 0) { out[OUT_KS] = ks; out[OUT_VS] = vs; }
  const float kinv = 1.0f / ks, vinv = 1.0f / vs;
  const size_t nchunks = 1048576;
  const size_t stride = (size_t)gridDim.x * blockDim.x;
  for (size_t ci = (size_t)blockIdx.x * blockDim.x + threadIdx.x; ci < nchunks; ci += stride) {
    const int d0 = (int)(ci & 7) * 8;
    const int t  = (int)(ci >> 3) & 2047;
    const int h  = (int)(ci >> 14) & 15;
    const int b  = (int)(ci >> 18);
    const size_t src = ((size_t)(b * Tn + t)) * C3n + h * HSn + d0;
    bf16x8 k8 = *(const bf16x8*)(qkv + src + Cn);
    bf16x8 v8 = *(const bf16x8*)(qkv + src + 2 * Cn);
    float kq[8], vq[8];
#pragma unroll
    for (int j = 0; j < 8; ++j) {
      kq[j] = fminf(fmaxf(rintf((float)k8[j] * kinv), -127.0f), 127.0f);
      vq[j] = fminf(fmaxf(rintf((float)v8[j] * vinv), -127.0f), 127.0f);
    }
    const size_t oi = ci * 8;
    f32x4 a0 = {kq[0], kq[1], kq[2], kq[3]};
    f32x4 a1 = {kq[4], kq[5], kq[6], kq[7]};
    *(f32x4*)(out + OUT_KQ + oi)     = a0;
    *(f32x4*)(out + OUT_KQ + oi + 4) = a1;
    float* vdst = out + OUT_VQ + oi;
#pragma unroll
    for (int j = 0; j < 8; ++j) vdst[j] = vq[j];
  }
}

// ============================================================
// Transposed-score MFMA flash attention, causal, q-tile=128 (2 q-groups/wave),
// double-buffered K/V. K/V fragments are wave-invariant -> amortized over 2
// q-groups. Block = (b,h,128 q rows), 4 waves. LDS 48 KB -> 3 blocks/CU.
__global__ __launch_bounds__(256, 3) void k_attn(const bf16* __restrict__ qkv,
                                                 bf16* __restrict__ y) {
  __shared__ bf16 Ks[2][64 * 64];
  __shared__ bf16 Vt[2][64 * 64];
  __shared__ bf16 Pt[4][2][16 * 64];   // per wave, per q-group

  const int tid = threadIdx.x;
  const int lane = tid & 63;
  const int w = tid >> 6;
  const int quad = lane >> 4;
  const int l15 = lane & 15;

  const int bh = blockIdx.x;               // fastest dim: big tiles dispatch first
  const int qt = 15 - (int)blockIdx.y;
  const int b = bh >> 4, h = bh & 15;
  const int q0 = qt * 128;
  const int ktMax = 2 * qt + 1;

  const bf16* qkv_b = qkv + (size_t)b * Tn * C3n + h * HSn;
  const bf16* kbase = qkv_b + Cn;
  const bf16* vbase = qkv_b + 2 * Cn;

  const int srow = lane >> 3;
  const int schunk = ((lane & 7) ^ srow) * 8;

  // ---- Q fragments for both groups (from global, once) ----
  const bf16* q0p = qkv_b + (size_t)(q0 + 16 * w + l15) * C3n;
  const bf16* q1p = q0p + (size_t)64 * C3n;
  bf16x8 qf[2][2];
  qf[0][0] = *(const bf16x8*)(q0p + quad * 8);
  qf[0][1] = *(const bf16x8*)(q0p + 32 + quad * 8);
  qf[1][0] = *(const bf16x8*)(q1p + quad * 8);
  qf[1][1] = *(const bf16x8*)(q1p + 32 + quad * 8);

  // ---- prologue: K(0), V(0) ----
  g2l16(kbase + (size_t)(8 * w + srow) * C3n + schunk, (bf16*)Ks[0] + w * 512);
  g2l16(kbase + (size_t)(8 * (w + 4) + srow) * C3n + schunk, (bf16*)Ks[0] + (w + 4) * 512);
  bf16x8 v0 = *(const bf16x8*)(vbase + (size_t)lane * C3n + w * 8);
  bf16x8 v1 = *(const bf16x8*)(vbase + (size_t)lane * C3n + (w + 4) * 8);
  __builtin_amdgcn_s_waitcnt(0);
#pragma unroll
  for (int j = 0; j < 8; ++j) {   // Vt[d][kc] swizzled; d&7 == j
    Vt[0][(w * 8 + j) * 64 + ((srow ^ j) << 3) + (lane & 7)] = v0[j];
    Vt[0][((w + 4) * 8 + j) * 64 + ((srow ^ j) << 3) + (lane & 7)] = v1[j];
  }
  __syncthreads();

  f32x4 Od[2][4] = {};
  float m_i[2] = {-INFINITY, -INFINITY};
  float l_i[2] = {0.0f, 0.0f};

  for (int kt = 0; kt <= ktMax; ++kt) {
    const int bsel = kt & 1;

    // ---- issue next tile's loads ----
    bf16x8 nv0, nv1;
    if (kt < ktMax) {
      const int kv1 = (kt + 1) * 64;
      g2l16(kbase + (size_t)(kv1 + 8 * w + srow) * C3n + schunk,
            (bf16*)Ks[bsel ^ 1] + w * 512);
      g2l16(kbase + (size_t)(kv1 + 8 * (w + 4) + srow) * C3n + schunk,
            (bf16*)Ks[bsel ^ 1] + (w + 4) * 512);
      nv0 = *(const bf16x8*)(vbase + (size_t)(kv1 + lane) * C3n + w * 8);
      nv1 = *(const bf16x8*)(vbase + (size_t)(kv1 + lane) * C3n + (w + 4) * 8);
    }

    // ---- S^T = K Q^T for both q-groups (K frags shared) ----
    const bf16* KsB = Ks[bsel];
    f32x4 S0[4] = {}, S1[4] = {};
#pragma unroll
    for (int ks = 0; ks < 2; ++ks)
#pragma unroll
      for (int nt = 0; nt < 4; ++nt) {
        const int rn = nt * 16 + l15;
        const int c = ((ks * 4 + quad) ^ (l15 & 7)) * 8;
        bf16x8 kf = *(const bf16x8*)(KsB + rn * 64 + c);
        S0[nt] = __builtin_amdgcn_mfma_f32_16x16x32_bf16(kf, qf[0][ks], S0[nt], 0, 0, 0);
        S1[nt] = __builtin_amdgcn_mfma_f32_16x16x32_bf16(kf, qf[1][ks], S1[nt], 0, 0, 0);
      }

    // ---- online softmax per group (lane owns q = g*64 + 16w + l15) ----
    const int qloc = 16 * w + l15;
    const int th[2] = { kt < 2 * qt ? 64 : (kt == 2 * qt ? qloc : -1),
                        kt < ktMax ? 64 : qloc };
    f32x4* Sg[2] = {S0, S1};
#pragma unroll
    for (int g = 0; g < 2; ++g) {
      float s[4][4];
      float mx = -INFINITY;
#pragma unroll
      for (int nt = 0; nt < 4; ++nt)
#pragma unroll
        for (int r = 0; r < 4; ++r) {
          float v = Sg[g][nt][r] * 0.125f;
          if (nt * 16 + quad * 4 + r > th[g]) v = -INFINITY;
          s[nt][r] = v;
          mx = fmaxf(mx, v);
        }
      mx = fmaxf(mx, __shfl_xor(mx, 16));
      mx = fmaxf(mx, __shfl_xor(mx, 32));
      const float mn = fmaxf(m_i[g], mx);
      const float al = __expf(m_i[g] - mn);
      m_i[g] = mn;
      float rsum = 0.0f;
      bf16x4 pk[4];
#pragma unroll
      for (int nt = 0; nt < 4; ++nt)
#pragma unroll
        for (int r = 0; r < 4; ++r) {
          const float p = __expf(s[nt][r] - mn);
          rsum += p;
          pk[nt][r] = (bf16)p;
        }
      rsum += __shfl_xor(rsum, 16);
      rsum += __shfl_xor(rsum, 32);
      l_i[g] = l_i[g] * al + rsum;
#pragma unroll
      for (int dt = 0; dt < 4; ++dt) Od[g][dt] *= al;
#pragma unroll
      for (int nt = 0; nt < 4; ++nt) {
        const int phys = (nt * 2 + (quad >> 1)) ^ (l15 & 7);
        *(bf16x4*)(&Pt[w][g][0] + l15 * 64 + phys * 8 + (quad & 1) * 4) = pk[nt];
      }
    }

    // ---- O^T += V^T P^T (V frags shared across groups) ----
    const bf16* VtB = Vt[bsel];
#pragma unroll
    for (int ks2 = 0; ks2 < 2; ++ks2) {
      const int pc = ((ks2 * 4 + quad) ^ (l15 & 7)) * 8;
      bf16x8 pf0 = *(const bf16x8*)(&Pt[w][0][0] + l15 * 64 + pc);
      bf16x8 pf1 = *(const bf16x8*)(&Pt[w][1][0] + l15 * 64 + pc);
#pragma unroll
      for (int dt = 0; dt < 4; ++dt) {
        const int d = dt * 16 + l15;
        bf16x8 vf = *(const bf16x8*)(VtB + d * 64 + pc);   // d&7 == l15&7
        Od[0][dt] = __builtin_amdgcn_mfma_f32_16x16x32_bf16(vf, pf0, Od[0][dt], 0, 0, 0);
        Od[1][dt] = __builtin_amdgcn_mfma_f32_16x16x32_bf16(vf, pf1, Od[1][dt], 0, 0, 0);
      }
    }

    // ---- drain next-tile loads, publish Vt[b^1], one barrier ----
    if (kt < ktMax) {
      __builtin_amdgcn_s_waitcnt(0);
#pragma unroll
      for (int j = 0; j < 8; ++j) {
        Vt[bsel ^ 1][(w * 8 + j) * 64 + ((srow ^ j) << 3) + (lane & 7)] = nv0[j];
        Vt[bsel ^ 1][((w + 4) * 8 + j) * 64 + ((srow ^ j) << 3) + (lane & 7)] = nv1[j];
      }
      __syncthreads();
    }
  }

  // ---- write y (B,T,C) ----
#pragma unroll
  for (int g = 0; g < 2; ++g) {
    const float invl = 1.0f / l_i[g];
    const size_t yb = ((size_t)b * Tn + q0 + g * 64 + 16 * w + l15) * Cn + h * HSn;
#pragma unroll
    for (int dt = 0; dt < 4; ++dt) {
      bf16x4 o;
#pragma unroll
      for (int r = 0; r < 4; ++r) o[r] = (bf16)(Od[g][dt][r] * invl);
      *(bf16x4*)(y + yb + dt * 16 + quad * 4) = o;
    }
  }
}

// ============================================================
extern "C" void kernel_launch(void* const* d_in, const int* in_sizes, int n_in,
                              void* d_out, int out_size, void* d_ws, size_t ws_size,
                              hipStream_t stream) {
  const float* x     = (const float*)d_in[0];
  const float* ln1w  = (const float*)d_in[1];
  const float* ln1b  = (const float*)d_in[2];
  const float* Wqkv  = (const float*)d_in[3];
  const float* bqkv  = (const float*)d_in[4];
  const float* Wo    = (const float*)d_in[5];
  const float* bo    = (const float*)d_in[6];
  const float* ln2w  = (const float*)d_in[7];
  const float* ln2b  = (const float*)d_in[8];
  const float* Wfc   = (const float*)d_in[9];
  const float* bfc   = (const float*)d_in[10];
  const float* Wpr   = (const float*)d_in[11];
  const float* bpr   = (const float*)d_in[12];

  char* ws = (char*)d_ws;
  bf16*  Wt_qkv = (bf16*)(ws + OFF_WT_QKV);
  bf16*  Wt_o   = (bf16*)(ws + OFF_WT_O);
  bf16*  Wt_fc  = (bf16*)(ws + OFF_WT_FC);
  bf16*  Wt_pr  = (bf16*)(ws + OFF_WT_PR);
  bf16*  h      = (bf16*)(ws + OFF_H);
  bf16*  ybf    = (bf16*)(ws + OFF_Y);
  float* x1     = (float*)(ws + OFF_X1);
  unsigned int* amax = (unsigned int*)(ws + OFF_AMAX);
  bf16*  qkvbf  = (bf16*)(ws + OFF_QKV);
  bf16*  g      = (bf16*)(ws + OFF_G);
  float* out    = (float*)d_out;

  const dim3 tb(32, 8);
  k_transpose<<<dim3(96, 32),  tb, 0, stream>>>(Wqkv, Wt_qkv, 1024, 3072);
  k_transpose<<<dim3(32, 32),  tb, 0, stream>>>(Wo,   Wt_o,   1024, 1024);
  k_transpose<<<dim3(128, 32), tb, 0, stream>>>(Wfc,  Wt_fc,  1024, 4096);
  k_transpose<<<dim3(32, 128), tb, 0, stream>>>(Wpr,  Wt_pr,  4096, 1024);
  k_init<<<1, 64, 0, stream>>>(amax);

  k_ln<<<BTn, 256, 0, stream>>>(x, ln1w, ln1b, h);
  // qkv = h @ Wqkv + b, fused per-tensor absmax of K,V
  // grid 64x24 = 1536 blocks = 3 exact rounds at 2 blocks/CU
  k_gemmT<false, false, true, false><<<dim3(64, 24), 512, 0, stream>>>(
      h, Wt_qkv, bqkv, nullptr, qkvbf, amax, 8192, 3072, 1024);
  k_quant<<<2048, 256, 0, stream>>>(qkvbf, amax, out);
  k_attn<<<dim3(64, 16), 256, 0, stream>>>(qkvbf, ybf);
  // x1 = y @ Wo + bo + x   (grid 64x8 = 512 = 1 exact round)
  k_gemmT<true, false, false, true><<<dim3(64, 8), 512, 0, stream>>>(
      ybf, Wt_o, bo, x, x1, nullptr, 8192, 1024, 1024);
  k_ln<<<BTn, 256, 0, stream>>>(x1, ln2w, ln2b, h);
  // g = gelu(h @ Wfc + b)   (grid 64x32 = 2048 = 4 exact rounds)
  k_gemmT<false, true, false, false><<<dim3(64, 32), 512, 0, stream>>>(
      h, Wt_fc, bfc, nullptr, g, nullptr, 8192, 4096, 1024);
  // out = g @ Wpr + bpr + x1   (grid 64x8 = 512 = 1 exact round)
  k_gemmT<true, false, false, true><<<dim3(64, 8), 512, 0, stream>>>(
      g, Wt_pr, bpr, x1, out, nullptr, 8192, 1024, 4096);
}

// Round 8
// 522.985 us; speedup vs baseline: 1.0567x; 1.0078x over previous
//
#include <hip/hip_runtime.h>
#include <cmath>

typedef __bf16 bf16;
typedef float f32x4 __attribute__((ext_vector_type(4)));
typedef __bf16 bf16x4 __attribute__((ext_vector_type(4)));
typedef __bf16 bf16x8 __attribute__((ext_vector_type(8)));

#define DEVI __device__ __forceinline__

// ---- problem dims ----
constexpr int Bn = 4, Tn = 2048, Cn = 1024, Hn = 16, HSn = 64;
constexpr int C3n = 3 * Cn;      // 3072
constexpr int BTn = Bn * Tn;     // 8192

// ---- workspace layout (bytes) ----
constexpr size_t OFF_WT_QKV = 0;           // 3072x1024 bf16
constexpr size_t OFF_WT_O   = 6291456;     // 1024x1024 bf16
constexpr size_t OFF_WT_FC  = 8388608;     // 4096x1024 bf16
constexpr size_t OFF_WT_PR  = 16777216;    // 1024x4096 bf16
constexpr size_t OFF_H      = 25165824;    // 8192x1024 bf16 (h / h2)
constexpr size_t OFF_Y      = 41943040;    // 8192x1024 bf16 (attn out)
constexpr size_t OFF_X1     = 58720256;    // 8192x1024 f32  (resid1)
constexpr size_t OFF_AMAX   = 92274688;    // 2 x u32
constexpr size_t OFF_QKV    = 92274944;    // 8192x3072 bf16
constexpr size_t OFF_G      = OFF_QKV;     // 8192x4096 bf16 (aliases qkv, dead by then)

// ---- d_out layout (float elements) ----
constexpr size_t OUT_X  = 0;          // (B,T,C)
constexpr size_t OUT_KQ = 8388608;    // (B,H,T,HS)
constexpr size_t OUT_KS = 16777216;   // scalar
constexpr size_t OUT_VQ = 16777217;   // (B,H,T,HS)
constexpr size_t OUT_VS = 25165825;   // scalar

// ============================================================
DEVI void g2l16(const void* g, void* l) {
  __builtin_amdgcn_global_load_lds(
      (__attribute__((address_space(1))) void*)g,
      (__attribute__((address_space(3))) void*)l, 16, 0, 0);
}

// exact-grade GELU: Abramowitz-Stegun 7.1.26 erf (|eps|<=1.5e-7), ~15 VALU + 1 exp
DEVI float gelu_f(float x) {
  const float ax = fabsf(x) * 0.7071067811865476f;
  const float t = 1.0f / (1.0f + 0.3275911f * ax);
  const float p = t * (0.254829592f + t * (-0.284496736f +
                  t * (1.421413741f + t * (-1.453152027f + t * 1.061405429f))));
  float er = 1.0f - p * __expf(-ax * ax);
  er = (x < 0.0f) ? -er : er;
  return 0.5f * x * (1.0f + er);
}

// ============================================================
// fused prep: all 4 weight transposes (f32 KxN -> bf16 NxK) + amax init.
// 1D grid of (32,8) blocks; ranges select the weight matrix.
struct TrJob { const float* W; bf16* Wt; int K, N, bx; };

__global__ __launch_bounds__(256) void k_prep(const float* W0, bf16* T0,
                                              const float* W1, bf16* T1,
                                              const float* W2, bf16* T2,
                                              const float* W3, bf16* T3,
                                              unsigned int* amax) {
  __shared__ float tile[32][33];
  const int id = blockIdx.x;
  if (id == 0 && threadIdx.x == 0 && threadIdx.y == 0) { amax[0] = 0u; amax[1] = 0u; }

  const float* W; bf16* Wt; int K, N, lid;
  if (id < 3072)      { W = W0; Wt = T0; K = 1024; N = 3072; lid = id; }
  else if (id < 4096) { W = W1; Wt = T1; K = 1024; N = 1024; lid = id - 3072; }
  else if (id < 8192) { W = W2; Wt = T2; K = 1024; N = 4096; lid = id - 4096; }
  else                { W = W3; Wt = T3; K = 4096; N = 1024; lid = id - 8192; }
  const int gx = N >> 5;
  const int n0 = (lid % gx) * 32, k0 = (lid / gx) * 32;
  const int tx = threadIdx.x, ty = threadIdx.y;   // block (32,8)
#pragma unroll
  for (int i = 0; i < 4; ++i) {
    int k = k0 + ty + i * 8;
    tile[ty + i * 8][tx] = W[(size_t)k * N + (n0 + tx)];
  }
  __syncthreads();
#pragma unroll
  for (int i = 0; i < 4; ++i) {
    int n = n0 + ty + i * 8;
    Wt[(size_t)n * K + (k0 + tx)] = (bf16)tile[tx][ty + i * 8];
  }
}

// ============================================================
// LayerNorm row of 1024, f32 in -> bf16 out.
__global__ __launch_bounds__(256) void k_ln(const float* __restrict__ x,
                                            const float* __restrict__ g,
                                            const float* __restrict__ b,
                                            bf16* __restrict__ out) {
  __shared__ float red[8];
  const int row = blockIdx.x, tid = threadIdx.x;
  const int lane = tid & 63, wv = tid >> 6;
  f32x4 v = ((const f32x4*)(x + (size_t)row * Cn))[tid];

  float s = v[0] + v[1] + v[2] + v[3];
  s += __shfl_down(s, 32); s += __shfl_down(s, 16); s += __shfl_down(s, 8);
  s += __shfl_down(s, 4);  s += __shfl_down(s, 2);  s += __shfl_down(s, 1);
  if (!lane) red[wv] = s;
  __syncthreads();
  const float mean = (red[0] + red[1] + red[2] + red[3]) * (1.0f / 1024.0f);
  __syncthreads();

  f32x4 d = v - mean;
  float s2 = d[0]*d[0] + d[1]*d[1] + d[2]*d[2] + d[3]*d[3];
  s2 += __shfl_down(s2, 32); s2 += __shfl_down(s2, 16); s2 += __shfl_down(s2, 8);
  s2 += __shfl_down(s2, 4);  s2 += __shfl_down(s2, 2);  s2 += __shfl_down(s2, 1);
  if (!lane) red[wv] = s2;
  __syncthreads();
  const float var = (red[0] + red[1] + red[2] + red[3]) * (1.0f / 1024.0f);
  const float inv = rsqrtf(var + 1e-5f);

  f32x4 gw = ((const f32x4*)g)[tid];
  f32x4 bb = ((const f32x4*)b)[tid];
  bf16x4 o;
#pragma unroll
  for (int j = 0; j < 4; ++j) o[j] = (bf16)(d[j] * inv * gw[j] + bb[j]);
  *(bf16x4*)(out + (size_t)row * Cn + tid * 4) = o;
}

// ============================================================
// 128x128-tile MFMA GEMM, BK=64, 512 threads (8 waves, 2M x 4N; wave tile 64x32).
// LDS = 4 x 16KB distinct buffers -> 64KB -> 2 blocks/CU. Distance-2 DMA
// double-buffer with counted vmcnt. COMPILER-SCHEDULED inner loop: no manual
// lgkm drains / sched_barrier / setprio (m97 evidence: compiler emits counted
// lgkmcnt interleaving ds_reads with MFMAs; manual lgkm0 exposed ~150cy/tile).
// Per K-tile:
//   {12 ds_reads + MFMA Q0,Q1}    (compiler interleaves, counted waits)
//   LGKM0; BARRIER                 (reads drained before DMA overwrites buf)
//   stage kt+2; MFMA Q2,Q3         (reg-only MFMAs overlap DMA issue)
//   VMCNT(4); BARRIER              (kt+1's DMA landed on all waves)
#define VMCNT(N) asm volatile("s_waitcnt vmcnt(" #N ")" ::: "memory")
#define LGKM0()  asm volatile("s_waitcnt lgkmcnt(0)" ::: "memory")
#define BARW()   asm volatile("s_barrier" ::: "memory")

DEVI void stage_half(const bf16* __restrict__ G, int ldk, int row0, int k0,
                     bf16* dst, int w, int lane) {
  const int srow = lane >> 3;
  const int sch = ((lane & 7) ^ srow) * 8;
  const bf16* src = G + (size_t)(row0 + srow) * ldk + k0 + sch;
#pragma unroll
  for (int i = 0; i < 2; ++i) {
    const int g = 2 * w + i;
    g2l16(src + (size_t)(8 * g) * ldk, dst + g * 512);
  }
}

DEVI void read_b(const bf16* BsB, int wn, int l15, int quad, bf16x8 (&bv)[2][2]) {
#pragma unroll
  for (int nt = 0; nt < 2; ++nt)
#pragma unroll
    for (int kk = 0; kk < 2; ++kk) {
      const int row = wn * 32 + nt * 16 + l15;
      const int c = ((kk * 4 + quad) ^ (l15 & 7)) * 8;
      bv[nt][kk] = *(const bf16x8*)(BsB + row * 64 + c);
    }
}

template <int Q>
DEVI void read_aq(const bf16* AsB, int wm, int l15, int quad, bf16x8 (&af)[2]) {
#pragma unroll
  for (int kk = 0; kk < 2; ++kk) {
    const int row = wm * 64 + Q * 16 + l15;
    const int c = ((kk * 4 + quad) ^ (l15 & 7)) * 8;
    af[kk] = *(const bf16x8*)(AsB + row * 64 + c);
  }
}

template <int Q>
DEVI void mfma_q(const bf16x8 (&af)[2], const bf16x8 (&bv)[2][2],
                 f32x4 (&acc)[4][2]) {
#pragma unroll
  for (int nt = 0; nt < 2; ++nt)
#pragma unroll
    for (int kk = 0; kk < 2; ++kk)
      acc[Q][nt] = __builtin_amdgcn_mfma_f32_16x16x32_bf16(
          af[kk], bv[nt][kk], acc[Q][nt], 0, 0, 0);
}

template <int BUF>
DEVI void tile_iter(int kt, int kIters, const bf16* __restrict__ A,
                    const bf16* __restrict__ Bt, int K, int m0, int n0,
                    bf16* As0, bf16* As1, bf16* Bs0, bf16* Bs1,
                    f32x4 (&acc)[4][2], int w, int lane) {
  const int l15 = lane & 15, quad = lane >> 4;
  const int wm = w >> 2, wn = w & 3;
  const bf16* AsB = BUF ? As1 : As0;   // read buffer (parity kt)
  const bf16* BsB = BUF ? Bs1 : Bs0;
  bf16* AsW = BUF ? As1 : As0;         // dest for tile kt+2 (same parity)
  bf16* BsW = BUF ? Bs1 : Bs0;

  bf16x8 bv[2][2];
  bf16x8 af0[2], af1[2], af2[2], af3[2];

  // ---- all fragment reads + first half of MFMAs (compiler-interleaved) ----
  read_b(BsB, wn, l15, quad, bv);
  read_aq<0>(AsB, wm, l15, quad, af0);
  read_aq<1>(AsB, wm, l15, quad, af1);
  read_aq<2>(AsB, wm, l15, quad, af2);
  read_aq<3>(AsB, wm, l15, quad, af3);
  mfma_q<0>(af0, bv, acc);
  mfma_q<1>(af1, bv, acc);

  // ---- drain reads, then allow buffer overwrite ----
  LGKM0();
  BARW();

  // ---- stage tile kt+2 (distance 2); reg-only MFMAs overlap DMA issue ----
  if (kt + 2 < kIters) {
    stage_half(A,  K, m0, (kt + 2) * 64, AsW, w, lane);
    stage_half(Bt, K, n0, (kt + 2) * 64, BsW, w, lane);
  }
  mfma_q<2>(af2, bv, acc);
  mfma_q<3>(af3, bv, acc);
  if (kt + 2 < kIters) {
    VMCNT(4);
    BARW();
  } else if (kt + 1 < kIters) {
    VMCNT(0);
    BARW();
  }
}

template <bool RES, bool GELU, bool AMAX, bool F32OUT>
__global__ __launch_bounds__(512, 4) void k_gemmT(const bf16* __restrict__ A,
                                                  const bf16* __restrict__ Bt,
                                                  const float* __restrict__ bias,
                                                  const float* __restrict__ res,
                                                  void* __restrict__ Cout,
                                                  unsigned int* __restrict__ amax,
                                                  int M, int N, int K) {
  __shared__ bf16 As0[128 * 64], As1[128 * 64];
  __shared__ bf16 Bs0[128 * 64], Bs1[128 * 64];
  __shared__ float redA[8];
  const int tid = threadIdx.x;
  const int lane = tid & 63, w = tid >> 6;
  const int wm = w >> 2, wn = w & 3;
  const int l15 = lane & 15, quad = lane >> 4;
  const int m0 = blockIdx.x * 128, n0 = blockIdx.y * 128;
  const int kIters = K >> 6;
  (void)M;

  // ---- prologue: tile0 -> buf0, tile1 -> buf1 ----
  stage_half(A,  K, m0, 0,  As0, w, lane);
  stage_half(Bt, K, n0, 0,  Bs0, w, lane);
  stage_half(A,  K, m0, 64, As1, w, lane);
  stage_half(Bt, K, n0, 64, Bs1, w, lane);
  VMCNT(4);
  BARW();

  f32x4 acc[4][2] = {};

  const int nPairs = kIters >> 1;
  for (int p = 0; p < nPairs; ++p) {
    tile_iter<0>(2 * p,     kIters, A, Bt, K, m0, n0, As0, As1, Bs0, Bs1, acc, w, lane);
    tile_iter<1>(2 * p + 1, kIters, A, Bt, K, m0, n0, As0, As1, Bs0, Bs1, acc, w, lane);
  }

  // ---- epilogue ----
  const int colB = n0 + wn * 32 + l15;
  const int rowB = m0 + wm * 64 + (quad << 2);
  float lm = 0.0f;
#pragma unroll
  for (int mt = 0; mt < 4; ++mt) {
#pragma unroll
    for (int nt = 0; nt < 2; ++nt) {
      const int col = colB + nt * 16;
      const float bval = bias[col];
#pragma unroll
      for (int r = 0; r < 4; ++r) {
        const int row = rowB + mt * 16 + r;
        float val = acc[mt][nt][r] + bval;
        if (GELU) val = gelu_f(val);
        if (RES)  val += res[(size_t)row * N + col];
        if (AMAX) lm = fmaxf(lm, fabsf(val));
        if (F32OUT) ((float*)Cout)[(size_t)row * N + col] = val;
        else        ((bf16*)Cout)[(size_t)row * N + col] = (bf16)val;
      }
    }
  }

  if (AMAX) {
    const int cls = n0 >> 10;   // 0=Q, 1=K, 2=V (128-tile never crosses a class)
    if (cls > 0) {
      lm = fmaxf(lm, __shfl_xor(lm, 1));
      lm = fmaxf(lm, __shfl_xor(lm, 2));
      lm = fmaxf(lm, __shfl_xor(lm, 4));
      lm = fmaxf(lm, __shfl_xor(lm, 8));
      lm = fmaxf(lm, __shfl_xor(lm, 16));
      lm = fmaxf(lm, __shfl_xor(lm, 32));
      if (!lane) redA[w] = lm;
      __syncthreads();
      if (tid == 0) {
        float m8 = redA[0];
#pragma unroll
        for (int i = 1; i < 8; ++i) m8 = fmaxf(m8, redA[i]);
        atomicMax(amax + (cls - 1), __float_as_uint(m8));
      }
    }
  }
}

// ============================================================
__global__ __launch_bounds__(256) void k_quant(const bf16* __restrict__ qkv,
                                               const unsigned int* __restrict__ amax,
                                               float* __restrict__ out) {
  const float ka = __uint_as_float(amax[0]);
  const float va = __uint_as_float(amax[1]);
  const float ks = ka > 0.0f ? ka / 127.0f : 1.0f;
  const float vs = va > 0.0f ? va / 127.0f : 1.0f;
  if (blockIdx.x == 0 && threadIdx.x == 0) { out[OUT_KS] = ks; out[OUT_VS] = vs; }
  const float kinv = 1.0f / ks, vinv = 1.0f / vs;
  const size_t nchunks = 1048576;
  const size_t stride = (size_t)gridDim.x * blockDim.x;
  for (size_t ci = (size_t)blockIdx.x * blockDim.x + threadIdx.x; ci < nchunks; ci += stride) {
    const int d0 = (int)(ci & 7) * 8;
    const int t  = (int)(ci >> 3) & 2047;
    const int h  = (int)(ci >> 14) & 15;
    const int b  = (int)(ci >> 18);
    const size_t src = ((size_t)(b * Tn + t)) * C3n + h * HSn + d0;
    bf16x8 k8 = *(const bf16x8*)(qkv + src + Cn);
    bf16x8 v8 = *(const bf16x8*)(qkv + src + 2 * Cn);
    float kq[8], vq[8];
#pragma unroll
    for (int j = 0; j < 8; ++j) {
      kq[j] = fminf(fmaxf(rintf((float)k8[j] * kinv), -127.0f), 127.0f);
      vq[j] = fminf(fmaxf(rintf((float)v8[j] * vinv), -127.0f), 127.0f);
    }
    const size_t oi = ci * 8;
    f32x4 a0 = {kq[0], kq[1], kq[2], kq[3]};
    f32x4 a1 = {kq[4], kq[5], kq[6], kq[7]};
    *(f32x4*)(out + OUT_KQ + oi)     = a0;
    *(f32x4*)(out + OUT_KQ + oi + 4) = a1;
    float* vdst = out + OUT_VQ + oi;
#pragma unroll
    for (int j = 0; j < 8; ++j) vdst[j] = vq[j];
  }
}

// ============================================================
// Transposed-score MFMA flash attention, causal, q-tile=128 (2 q-groups/wave),
// double-buffered K/V. K/V fragments are wave-invariant -> amortized over 2
// q-groups. Block = (b,h,128 q rows), 4 waves. LDS 48 KB -> 3 blocks/CU.
__global__ __launch_bounds__(256, 3) void k_attn(const bf16* __restrict__ qkv,
                                                 bf16* __restrict__ y) {
  __shared__ bf16 Ks[2][64 * 64];
  __shared__ bf16 Vt[2][64 * 64];
  __shared__ bf16 Pt[4][2][16 * 64];   // per wave, per q-group

  const int tid = threadIdx.x;
  const int lane = tid & 63;
  const int w = tid >> 6;
  const int quad = lane >> 4;
  const int l15 = lane & 15;

  const int bh = blockIdx.x;               // fastest dim: big tiles dispatch first
  const int qt = 15 - (int)blockIdx.y;
  const int b = bh >> 4, h = bh & 15;
  const int q0 = qt * 128;
  const int ktMax = 2 * qt + 1;

  const bf16* qkv_b = qkv + (size_t)b * Tn * C3n + h * HSn;
  const bf16* kbase = qkv_b + Cn;
  const bf16* vbase = qkv_b + 2 * Cn;

  const int srow = lane >> 3;
  const int schunk = ((lane & 7) ^ srow) * 8;

  // ---- Q fragments for both groups (from global, once) ----
  const bf16* q0p = qkv_b + (size_t)(q0 + 16 * w + l15) * C3n;
  const bf16* q1p = q0p + (size_t)64 * C3n;
  bf16x8 qf[2][2];
  qf[0][0] = *(const bf16x8*)(q0p + quad * 8);
  qf[0][1] = *(const bf16x8*)(q0p + 32 + quad * 8);
  qf[1][0] = *(const bf16x8*)(q1p + quad * 8);
  qf[1][1] = *(const bf16x8*)(q1p + 32 + quad * 8);

  // ---- prologue: K(0), V(0) ----
  g2l16(kbase + (size_t)(8 * w + srow) * C3n + schunk, (bf16*)Ks[0] + w * 512);
  g2l16(kbase + (size_t)(8 * (w + 4) + srow) * C3n + schunk, (bf16*)Ks[0] + (w + 4) * 512);
  bf16x8 v0 = *(const bf16x8*)(vbase + (size_t)lane * C3n + w * 8);
  bf16x8 v1 = *(const bf16x8*)(vbase + (size_t)lane * C3n + (w + 4) * 8);
  __builtin_amdgcn_s_waitcnt(0);
#pragma unroll
  for (int j = 0; j < 8; ++j) {   // Vt[d][kc] swizzled; d&7 == j
    Vt[0][(w * 8 + j) * 64 + ((srow ^ j) << 3) + (lane & 7)] = v0[j];
    Vt[0][((w + 4) * 8 + j) * 64 + ((srow ^ j) << 3) + (lane & 7)] = v1[j];
  }
  __syncthreads();

  f32x4 Od[2][4] = {};
  float m_i[2] = {-INFINITY, -INFINITY};
  float l_i[2] = {0.0f, 0.0f};

  for (int kt = 0; kt <= ktMax; ++kt) {
    const int bsel = kt & 1;

    // ---- issue next tile's loads ----
    bf16x8 nv0, nv1;
    if (kt < ktMax) {
      const int kv1 = (kt + 1) * 64;
      g2l16(kbase + (size_t)(kv1 + 8 * w + srow) * C3n + schunk,
            (bf16*)Ks[bsel ^ 1] + w * 512);
      g2l16(kbase + (size_t)(kv1 + 8 * (w + 4) + srow) * C3n + schunk,
            (bf16*)Ks[bsel ^ 1] + (w + 4) * 512);
      nv0 = *(const bf16x8*)(vbase + (size_t)(kv1 + lane) * C3n + w * 8);
      nv1 = *(const bf16x8*)(vbase + (size_t)(kv1 + lane) * C3n + (w + 4) * 8);
    }

    // ---- S^T = K Q^T for both q-groups (K frags shared) ----
    const bf16* KsB = Ks[bsel];
    f32x4 S0[4] = {}, S1[4] = {};
#pragma unroll
    for (int ks = 0; ks < 2; ++ks)
#pragma unroll
      for (int nt = 0; nt < 4; ++nt) {
        const int rn = nt * 16 + l15;
        const int c = ((ks * 4 + quad) ^ (l15 & 7)) * 8;
        bf16x8 kf = *(const bf16x8*)(KsB + rn * 64 + c);
        S0[nt] = __builtin_amdgcn_mfma_f32_16x16x32_bf16(kf, qf[0][ks], S0[nt], 0, 0, 0);
        S1[nt] = __builtin_amdgcn_mfma_f32_16x16x32_bf16(kf, qf[1][ks], S1[nt], 0, 0, 0);
      }

    // ---- online softmax per group (lane owns q = g*64 + 16w + l15) ----
    const int qloc = 16 * w + l15;
    const int th[2] = { kt < 2 * qt ? 64 : (kt == 2 * qt ? qloc : -1),
                        kt < ktMax ? 64 : qloc };
    f32x4* Sg[2] = {S0, S1};
#pragma unroll
    for (int g = 0; g < 2; ++g) {
      float s[4][4];
      float mx = -INFINITY;
#pragma unroll
      for (int nt = 0; nt < 4; ++nt)
#pragma unroll
        for (int r = 0; r < 4; ++r) {
          float v = Sg[g][nt][r] * 0.125f;
          if (nt * 16 + quad * 4 + r > th[g]) v = -INFINITY;
          s[nt][r] = v;
          mx = fmaxf(mx, v);
        }
      mx = fmaxf(mx, __shfl_xor(mx, 16));
      mx = fmaxf(mx, __shfl_xor(mx, 32));
      const float mn = fmaxf(m_i[g], mx);
      const float al = __expf(m_i[g] - mn);
      m_i[g] = mn;
      float rsum = 0.0f;
      bf16x4 pk[4];
#pragma unroll
      for (int nt = 0; nt < 4; ++nt)
#pragma unroll
        for (int r = 0; r < 4; ++r) {
          const float p = __expf(s[nt][r] - mn);
          rsum += p;
          pk[nt][r] = (bf16)p;
        }
      rsum += __shfl_xor(rsum, 16);
      rsum += __shfl_xor(rsum, 32);
      l_i[g] = l_i[g] * al + rsum;
#pragma unroll
      for (int dt = 0; dt < 4; ++dt) Od[g][dt] *= al;
#pragma unroll
      for (int nt = 0; nt < 4; ++nt) {
        const int phys = (nt * 2 + (quad >> 1)) ^ (l15 & 7);
        *(bf16x4*)(&Pt[w][g][0] + l15 * 64 + phys * 8 + (quad & 1) * 4) = pk[nt];
      }
    }

    // ---- O^T += V^T P^T (V frags shared across groups) ----
    const bf16* VtB = Vt[bsel];
#pragma unroll
    for (int ks2 = 0; ks2 < 2; ++ks2) {
      const int pc = ((ks2 * 4 + quad) ^ (l15 & 7)) * 8;
      bf16x8 pf0 = *(const bf16x8*)(&Pt[w][0][0] + l15 * 64 + pc);
      bf16x8 pf1 = *(const bf16x8*)(&Pt[w][1][0] + l15 * 64 + pc);
#pragma unroll
      for (int dt = 0; dt < 4; ++dt) {
        const int d = dt * 16 + l15;
        bf16x8 vf = *(const bf16x8*)(VtB + d * 64 + pc);   // d&7 == l15&7
        Od[0][dt] = __builtin_amdgcn_mfma_f32_16x16x32_bf16(vf, pf0, Od[0][dt], 0, 0, 0);
        Od[1][dt] = __builtin_amdgcn_mfma_f32_16x16x32_bf16(vf, pf1, Od[1][dt], 0, 0, 0);
      }
    }

    // ---- drain next-tile loads, publish Vt[b^1], one barrier ----
    if (kt < ktMax) {
      __builtin_amdgcn_s_waitcnt(0);
#pragma unroll
      for (int j = 0; j < 8; ++j) {
        Vt[bsel ^ 1][(w * 8 + j) * 64 + ((srow ^ j) << 3) + (lane & 7)] = nv0[j];
        Vt[bsel ^ 1][((w + 4) * 8 + j) * 64 + ((srow ^ j) << 3) + (lane & 7)] = nv1[j];
      }
      __syncthreads();
    }
  }

  // ---- write y (B,T,C) ----
#pragma unroll
  for (int g = 0; g < 2; ++g) {
    const float invl = 1.0f / l_i[g];
    const size_t yb = ((size_t)b * Tn + q0 + g * 64 + 16 * w + l15) * Cn + h * HSn;
#pragma unroll
    for (int dt = 0; dt < 4; ++dt) {
      bf16x4 o;
#pragma unroll
      for (int r = 0; r < 4; ++r) o[r] = (bf16)(Od[g][dt][r] * invl);
      *(bf16x4*)(y + yb + dt * 16 + quad * 4) = o;
    }
  }
}

// ============================================================
extern "C" void kernel_launch(void* const* d_in, const int* in_sizes, int n_in,
                              void* d_out, int out_size, void* d_ws, size_t ws_size,
                              hipStream_t stream) {
  const float* x     = (const float*)d_in[0];
  const float* ln1w  = (const float*)d_in[1];
  const float* ln1b  = (const float*)d_in[2];
  const float* Wqkv  = (const float*)d_in[3];
  const float* bqkv  = (const float*)d_in[4];
  const float* Wo    = (const float*)d_in[5];
  const float* bo    = (const float*)d_in[6];
  const float* ln2w  = (const float*)d_in[7];
  const float* ln2b  = (const float*)d_in[8];
  const float* Wfc   = (const float*)d_in[9];
  const float* bfc   = (const float*)d_in[10];
  const float* Wpr   = (const float*)d_in[11];
  const float* bpr   = (const float*)d_in[12];

  char* ws = (char*)d_ws;
  bf16*  Wt_qkv = (bf16*)(ws + OFF_WT_QKV);
  bf16*  Wt_o   = (bf16*)(ws + OFF_WT_O);
  bf16*  Wt_fc  = (bf16*)(ws + OFF_WT_FC);
  bf16*  Wt_pr  = (bf16*)(ws + OFF_WT_PR);
  bf16*  h      = (bf16*)(ws + OFF_H);
  bf16*  ybf    = (bf16*)(ws + OFF_Y);
  float* x1     = (float*)(ws + OFF_X1);
  unsigned int* amax = (unsigned int*)(ws + OFF_AMAX);
  bf16*  qkvbf  = (bf16*)(ws + OFF_QKV);
  bf16*  g      = (bf16*)(ws + OFF_G);
  float* out    = (float*)d_out;

  // fused weight transposes + amax init (1 launch instead of 5)
  k_prep<<<dim3(12288), dim3(32, 8), 0, stream>>>(Wqkv, Wt_qkv, Wo, Wt_o,
                                                  Wfc, Wt_fc, Wpr, Wt_pr, amax);

  k_ln<<<BTn, 256, 0, stream>>>(x, ln1w, ln1b, h);
  // qkv = h @ Wqkv + b, fused per-tensor absmax of K,V
  k_gemmT<false, false, true, false><<<dim3(64, 24), 512, 0, stream>>>(
      h, Wt_qkv, bqkv, nullptr, qkvbf, amax, 8192, 3072, 1024);
  k_quant<<<2048, 256, 0, stream>>>(qkvbf, amax, out);
  k_attn<<<dim3(64, 16), 256, 0, stream>>>(qkvbf, ybf);
  // x1 = y @ Wo + bo + x
  k_gemmT<true, false, false, true><<<dim3(64, 8), 512, 0, stream>>>(
      ybf, Wt_o, bo, x, x1, nullptr, 8192, 1024, 1024);
  k_ln<<<BTn, 256, 0, stream>>>(x1, ln2w, ln2b, h);
  // g = gelu(h @ Wfc + b)
  k_gemmT<false, true, false, false><<<dim3(64, 32), 512, 0, stream>>>(
      h, Wt_fc, bfc, nullptr, g, nullptr, 8192, 4096, 1024);
  // out = g @ Wpr + bpr + x1
  k_gemmT<true, false, false, true><<<dim3(64, 8), 512, 0, stream>>>(
      g, Wt_pr, bpr, x1, out, nullptr, 8192, 1024, 4096);
}